// Round 1
// baseline (520.324 us; speedup 1.0000x reference)
//
#include <hip/hip_runtime.h>

#define NPTS   131072
#define CIN    1018
#define DIN    1024
#define COUT   128
#define BB     16
#define GDIM   32
#define NCELLS (BB*GDIM*GDIM*GDIM)   // 524288

typedef float          f32x4  __attribute__((ext_vector_type(4)));
typedef __bf16         bf16x8 __attribute__((ext_vector_type(8)));
typedef unsigned short us8    __attribute__((ext_vector_type(8)));

__device__ __forceinline__ unsigned short f2bf(float f) {
    union { float f; unsigned u; } v; v.f = f;
    unsigned r = v.u + 0x7FFFu + ((v.u >> 16) & 1u);   // RNE
    return (unsigned short)(r >> 16);
}

// ---- pack W1 (1024x128 f32) into MFMA-B-fragment-ordered bf16 --------------
// packed[((ks*8+cb)*64 + lane)*8 + i] = bf16( W1[ks*32 + (lane>>4)*8 + i][cb*16 + (lane&15)] )
__global__ __launch_bounds__(256) void k_packW(const float* __restrict__ W1,
                                               unsigned short* __restrict__ pw) {
    const int t  = blockIdx.x * 256 + threadIdx.x;   // 0..16383
    const int l  = t & 63;
    const int cb = (t >> 6) & 7;
    const int ks = t >> 9;
    const int col  = cb * 16 + (l & 15);
    const int krow = ks * 32 + ((l >> 4) * 8);
    unsigned short* dst = pw + (size_t)t * 8;
#pragma unroll
    for (int i = 0; i < 8; ++i) dst[i] = f2bf(W1[(size_t)(krow + i) * COUT + col]);
}

// ---- prep: cell ids, tail columns (offset|xyz), counts, zero touched cells --
__global__ __launch_bounds__(256) void k_prep(const float* __restrict__ xyz,
                                              const float* __restrict__ nocs,
                                              const int*   __restrict__ bidx,
                                              float* __restrict__ tail,
                                              int*   __restrict__ cellid,
                                              float* __restrict__ count,
                                              float* __restrict__ cellsum,
                                              int zero_cs) {
    const int i = blockIdx.x * 256 + threadIdx.x;
    if (i >= NPTS) return;
    int id[3]; float off[3];
#pragma unroll
    for (int d = 0; d < 3; ++d) {
        const float nv = nocs[i * 3 + d];
        int ii = (int)rintf(nv * 31.0f);              // jnp.round = half-to-even = rintf
        ii = ii < 0 ? 0 : (ii > 31 ? 31 : ii);
        id[d]  = ii;
        off[d] = nv - (float)ii / 31.0f;
    }
    float* tl = tail + (size_t)i * 8;
    tl[0] = off[0]; tl[1] = off[1]; tl[2] = off[2];
    tl[3] = xyz[i*3+0]; tl[4] = xyz[i*3+1]; tl[5] = xyz[i*3+2];
    tl[6] = 0.f; tl[7] = 0.f;
    const int cell = ((bidx[i] * GDIM + id[0]) * GDIM + id[1]) * GDIM + id[2];
    cellid[i] = cell;
    unsafeAtomicAdd(count + cell, 1.0f);
    if (zero_cs) {                       // zero only touched cells (saves 256MB memset)
        f32x4* p = (f32x4*)(cellsum + (size_t)cell * COUT);
        f32x4 z; z[0] = z[1] = z[2] = z[3] = 0.f;
#pragma unroll
        for (int q = 0; q < 32; ++q) p[q] = z;
    }
}

// ---- fused GEMM(bf16 MFMA) + bias + relu + scatter + BN stats ---------------
// block = 256 thr (4 waves). Tile: 128 rows x 128 cols, K-chunks of 64.
// wave w owns rows [w*32, w*32+32): two 16-row subtiles.
template<int DIRECT>
__global__ __launch_bounds__(256) void k_gemm(const float* __restrict__ feats,
                                              const float* __restrict__ tail,
                                              const int*   __restrict__ cellid,
                                              const float* __restrict__ b1,
                                              const unsigned short* __restrict__ pw,
                                              float* __restrict__ dst,   // cellsum (A) or out (B)
                                              float* __restrict__ gstats) {
    __shared__ unsigned short Alds[128 * 72];        // 64 k-cols + 8 pad shorts
    __shared__ unsigned short Blds[2 * 8 * 64 * 8];  // [ks][cb][lane][8]
    __shared__ float lsum[COUT];
    __shared__ float lsq[COUT];
    const int t = threadIdx.x;
    const int w = t >> 6, l = t & 63;
    const int kgrp = l >> 4, l15 = l & 15;
    const int row0 = blockIdx.x * 128;
    if (t < COUT) { lsum[t] = 0.f; lsq[t] = 0.f; }
    f32x4 acc0[8], acc1[8];
#pragma unroll
    for (int cb = 0; cb < 8; ++cb) {
#pragma unroll
        for (int d = 0; d < 4; ++d) { acc0[cb][d] = 0.f; acc1[cb][d] = 0.f; }
    }
    const int lr0 = w * 32 + l15, lr1 = lr0 + 16;
    const int kh = t & 31, rr = t >> 5;

    for (int ch = 0; ch < 16; ++ch) {
        const int k0 = ch * 64;
        __syncthreads();
        // stage A: 128 rows x 64 k (f32 -> bf16), float2 per thread per rep
#pragma unroll
        for (int rep = 0; rep < 16; ++rep) {
            const int r  = rr + rep * 8;
            const int g  = row0 + r;
            const int kg = k0 + kh * 2;
            const float2* src = (kg < CIN)
                ? (const float2*)(feats + (size_t)g * CIN + kg)
                : (const float2*)(tail  + (size_t)g * 8   + (kg - CIN));
            const float2 v = *src;
            const unsigned pk = (unsigned)f2bf(v.x) | ((unsigned)f2bf(v.y) << 16);
            *(unsigned*)&Alds[r * 72 + kh * 2] = pk;
        }
        // stage B: 16 KB of pre-packed bf16 fragments
        {
            const unsigned short* src = pw + (size_t)ch * (2 * 8 * 64 * 8);
#pragma unroll
            for (int i = 0; i < 4; ++i) {
                const int u16 = t + i * 256;
                *(us8*)&Blds[u16 * 8] = *(const us8*)&src[u16 * 8];
            }
        }
        __syncthreads();
#pragma unroll
        for (int ks = 0; ks < 2; ++ks) {
            const us8 a0 = *(const us8*)&Alds[lr0 * 72 + ks * 32 + kgrp * 8];
            const us8 a1 = *(const us8*)&Alds[lr1 * 72 + ks * 32 + kgrp * 8];
#pragma unroll
            for (int cb = 0; cb < 8; ++cb) {
                const us8 b = *(const us8*)&Blds[((ks * 8 + cb) * 64 + l) * 8];
                acc0[cb] = __builtin_amdgcn_mfma_f32_16x16x32_bf16(
                    __builtin_bit_cast(bf16x8, a0), __builtin_bit_cast(bf16x8, b), acc0[cb], 0, 0, 0);
                acc1[cb] = __builtin_amdgcn_mfma_f32_16x16x32_bf16(
                    __builtin_bit_cast(bf16x8, a1), __builtin_bit_cast(bf16x8, b), acc1[cb], 0, 0, 0);
            }
        }
    }
    // epilogue: bias+relu, scatter to cells, accumulate BN stats
    int c0[4], c1[4];
#pragma unroll
    for (int j = 0; j < 4; ++j) {
        const int m = w * 32 + kgrp * 4 + j;    // C/D: row=(lane>>4)*4+reg, col=lane&15
        c0[j] = cellid[row0 + m];
        c1[j] = cellid[row0 + m + 16];
    }
#pragma unroll
    for (int cb = 0; cb < 8; ++cb) {
        const int c = cb * 16 + l15;
        const float bias = b1[c];
        float s = 0.f, q = 0.f;
#pragma unroll
        for (int j = 0; j < 4; ++j) {
            float v0 = acc0[cb][j] + bias; v0 = v0 > 0.f ? v0 : 0.f;
            float v1 = acc1[cb][j] + bias; v1 = v1 > 0.f ? v1 : 0.f;
            if (DIRECT) {
                const int a = c0[j], bce = c1[j];
                unsafeAtomicAdd(dst + (((size_t)((a  >> 15) * COUT + c)) << 15) + (a  & 32767), v0);
                unsafeAtomicAdd(dst + (((size_t)((bce >> 15) * COUT + c)) << 15) + (bce & 32767), v1);
            } else {
                unsafeAtomicAdd(dst + (size_t)c0[j] * COUT + c, v0);
                unsafeAtomicAdd(dst + (size_t)c1[j] * COUT + c, v1);
            }
            s += v0 + v1; q += v0 * v0 + v1 * v1;
        }
        s += __shfl_xor(s, 16); s += __shfl_xor(s, 32);
        q += __shfl_xor(q, 16); q += __shfl_xor(q, 32);
        if (l < 16) { atomicAdd(&lsum[c], s); atomicAdd(&lsq[c], q); }
    }
    __syncthreads();
    if (t < COUT) {
        unsafeAtomicAdd(gstats + t, lsum[t]);
        unsafeAtomicAdd(gstats + COUT + t, lsq[t]);
    }
}

// ---- finalize BN affine: scale/shift per channel ---------------------------
__global__ void k_stats(const float* __restrict__ gstats, const float* __restrict__ g1,
                        const float* __restrict__ be1, float* __restrict__ ss) {
    const int c = threadIdx.x;   // 128
    const float invn = 1.0f / (float)NPTS;
    const float mean = gstats[c] * invn;
    float var = gstats[COUT + c] * invn - mean * mean;
    var = var < 0.f ? 0.f : var;
    const float sc = g1[c] * rsqrtf(var + 1e-5f);
    ss[c] = sc;
    ss[COUT + c] = be1[c] - mean * sc;
}

// ---- transpose [cell][c] -> [b][c][spatial] with mean + BN affine ----------
__global__ __launch_bounds__(256) void k_out(const float* __restrict__ cellsum,
                                             const float* __restrict__ count,
                                             const float* __restrict__ ss,
                                             float* __restrict__ out) {
    __shared__ float tile[128 * 128];   // addr(c,j) = c*128 + (j ^ (c&28))
    __shared__ float linv[128];
    __shared__ float lss[256];
    const int t  = threadIdx.x;
    const int s0 = blockIdx.x * 128;
    const int b = s0 >> 15, sp0 = s0 & 32767;
    if (t < 128) {
        const float cn = count[s0 + t];
        linv[t] = cn > 0.f ? 1.0f / cn : 0.f;
    } else {
        const int c = t - 128;
        lss[c] = ss[c]; lss[128 + c] = ss[COUT + c];
    }
    const int q = t & 31, r8 = t >> 5;
#pragma unroll
    for (int rep = 0; rep < 16; ++rep) {
        const int j = r8 + rep * 8;
        const f32x4 v = *(const f32x4*)&cellsum[(size_t)(s0 + j) * COUT + q * 4];
#pragma unroll
        for (int d = 0; d < 4; ++d) {
            const int c = q * 4 + d;
            tile[c * 128 + (j ^ (c & 28))] = v[d];
        }
    }
    __syncthreads();
#pragma unroll
    for (int p = 0; p < 16; ++p) {
        const int c = p * 8 + r8;
        const float sc = lss[c], sh = lss[128 + c];
        const int u = c & 28;
        const f32x4 vv = *(const f32x4*)&tile[c * 128 + ((q * 4) ^ u)];
        f32x4 o;
#pragma unroll
        for (int d = 0; d < 4; ++d) {
            const float inv = linv[q * 4 + d];
            o[d] = inv > 0.f ? vv[d] * inv * sc + sh : 0.f;
        }
        *(f32x4*)&out[(((size_t)(b * COUT + c)) << 15) + sp0 + q * 4] = o;
    }
}

// ---- fallback normalize when ws too small (scatter went straight to out) ---
__global__ __launch_bounds__(256) void k_norm_inplace(float* __restrict__ out,
                                                      const float* __restrict__ count,
                                                      const float* __restrict__ ss,
                                                      size_t total) {
    const size_t i = ((size_t)blockIdx.x * 256 + threadIdx.x) * 4;
    if (i >= total) return;
    const int c = (int)((i >> 15) & 127);
    const size_t cellb = ((i >> 22) << 15) | (i & 32767);
    f32x4 v = *(f32x4*)&out[i];
    const f32x4 cn = *(const f32x4*)&count[cellb];
    const float sc = ss[c], sh = ss[COUT + c];
#pragma unroll
    for (int d = 0; d < 4; ++d) v[d] = cn[d] > 0.f ? v[d] / cn[d] * sc + sh : 0.f;
    *(f32x4*)&out[i] = v;
}

extern "C" void kernel_launch(void* const* d_in, const int* in_sizes, int n_in,
                              void* d_out, int out_size, void* d_ws, size_t ws_size,
                              hipStream_t stream) {
    const float* xyz   = (const float*)d_in[0];
    const float* nocs  = (const float*)d_in[1];
    const float* feats = (const float*)d_in[2];
    const int*   bidx  = (const int*)d_in[4];
    const float* W1    = (const float*)d_in[6];
    const float* b1    = (const float*)d_in[7];
    const float* g1    = (const float*)d_in[8];
    const float* be1   = (const float*)d_in[9];
    float* out = (float*)d_out;
    float* ws  = (float*)d_ws;

    const size_t CSF = (size_t)NCELLS * COUT;             // 67,108,864 floats
    // plan A layout (floats): cellsum | count | stats | ss | tail | cellid | packedW
    const size_t oA_cs   = 0;
    const size_t oA_cnt  = CSF;
    const size_t oA_st   = oA_cnt + NCELLS;
    const size_t oA_ss   = oA_st + 256;
    const size_t oA_tail = oA_ss + 256;
    const size_t oA_cid  = oA_tail + (size_t)NPTS * 8;
    const size_t oA_pw   = oA_cid + NPTS;
    const size_t needA   = (oA_pw + 65536) * sizeof(float);   // packedW = 131072 u16
    const bool planA = ws_size >= needA;

    // plan B layout (floats): count | stats | ss | tail | cellid | packedW
    const size_t oB_cnt = 0, oB_st = NCELLS, oB_ss = oB_st + 256,
                 oB_tail = oB_ss + 256, oB_cid = oB_tail + (size_t)NPTS * 8,
                 oB_pw = oB_cid + NPTS;

    float* cs  = planA ? ws + oA_cs : nullptr;
    float* cnt = ws + (planA ? oA_cnt : oB_cnt);
    float* st  = ws + (planA ? oA_st : oB_st);
    float* ssb = ws + (planA ? oA_ss : oB_ss);
    float* tl  = ws + (planA ? oA_tail : oB_tail);
    int*   cid = (int*)(ws + (planA ? oA_cid : oB_cid));
    unsigned short* pw = (unsigned short*)(ws + (planA ? oA_pw : oB_pw));

    // zero count + stats (contiguous)
    hipMemsetAsync(cnt, 0, (NCELLS + 256) * sizeof(float), stream);
    if (!planA) hipMemsetAsync(out, 0, (size_t)out_size * sizeof(float), stream);

    k_packW<<<64, 256, 0, stream>>>(W1, pw);
    k_prep<<<NPTS / 256, 256, 0, stream>>>(xyz, nocs, bidx, tl, cid, cnt,
                                           planA ? cs : cnt, planA ? 1 : 0);
    if (planA)
        k_gemm<0><<<NPTS / 128, 256, 0, stream>>>(feats, tl, cid, b1, pw, cs, st);
    else
        k_gemm<1><<<NPTS / 128, 256, 0, stream>>>(feats, tl, cid, b1, pw, out, st);
    k_stats<<<1, 128, 0, stream>>>(st, g1, be1, ssb);
    if (planA)
        k_out<<<NCELLS / 128, 256, 0, stream>>>(cs, cnt, ssb, out);
    else {
        const size_t total = (size_t)out_size;
        k_norm_inplace<<<(unsigned)((total + 1023) / 1024), 256, 0, stream>>>(out, cnt, ssb, total);
    }
    (void)in_sizes; (void)n_in; (void)ws_size; (void)d_in;
}

// Round 2
// 383.538 us; speedup vs baseline: 1.3566x; 1.3566x over previous
//
#include <hip/hip_runtime.h>

#define NPTS   131072
#define CIN    1018
#define DIN    1024
#define COUT   128
#define BB     16
#define GDIM   32
#define NCELLS (BB*GDIM*GDIM*GDIM)   // 524288

typedef float          f32x4  __attribute__((ext_vector_type(4)));
typedef __bf16         bf16x8 __attribute__((ext_vector_type(8)));
typedef unsigned short us8    __attribute__((ext_vector_type(8)));

__device__ __forceinline__ unsigned short f2bf(float f) {
    union { float f; unsigned u; } v; v.f = f;
    unsigned r = v.u + 0x7FFFu + ((v.u >> 16) & 1u);   // RNE
    return (unsigned short)(r >> 16);
}

// ---- pack W1 (1024x128 f32) into MFMA-B-fragment-ordered bf16 --------------
// packed[((ksg*8+cb)*64 + lane)*8 + i] = bf16( W1[ksg*32 + (lane>>4)*8 + i][cb*16 + (lane&15)] )
__global__ __launch_bounds__(256) void k_packW(const float* __restrict__ W1,
                                               unsigned short* __restrict__ pw) {
    const int t  = blockIdx.x * 256 + threadIdx.x;   // 0..16383
    const int l  = t & 63;
    const int cb = (t >> 6) & 7;
    const int ks = t >> 9;
    const int col  = cb * 16 + (l & 15);
    const int krow = ks * 32 + ((l >> 4) * 8);
    unsigned short* dst = pw + (size_t)t * 8;
#pragma unroll
    for (int i = 0; i < 8; ++i) dst[i] = f2bf(W1[(size_t)(krow + i) * COUT + col]);
}

// ---- prep: cell ids, tail group {f1016,f1017,off*3,xyz*3}, counts, zero cells
__global__ __launch_bounds__(256) void k_prep(const float* __restrict__ xyz,
                                              const float* __restrict__ nocs,
                                              const float* __restrict__ feats,
                                              const int*   __restrict__ bidx,
                                              float* __restrict__ tail,
                                              int*   __restrict__ cellid,
                                              float* __restrict__ count,
                                              float* __restrict__ cellsum,
                                              int zero_cs) {
    const int i = blockIdx.x * 256 + threadIdx.x;
    if (i >= NPTS) return;
    int id[3]; float off[3];
#pragma unroll
    for (int d = 0; d < 3; ++d) {
        const float nv = nocs[i * 3 + d];
        int ii = (int)rintf(nv * 31.0f);              // jnp.round = half-to-even = rintf
        ii = ii < 0 ? 0 : (ii > 31 ? 31 : ii);
        id[d]  = ii;
        off[d] = nv - (float)ii / 31.0f;
    }
    float* tl = tail + (size_t)i * 8;
    tl[0] = feats[(size_t)i * CIN + 1016];
    tl[1] = feats[(size_t)i * CIN + 1017];
    tl[2] = off[0]; tl[3] = off[1]; tl[4] = off[2];
    tl[5] = xyz[i*3+0]; tl[6] = xyz[i*3+1]; tl[7] = xyz[i*3+2];
    const int cell = ((bidx[i] * GDIM + id[0]) * GDIM + id[1]) * GDIM + id[2];
    cellid[i] = cell;
    unsafeAtomicAdd(count + cell, 1.0f);
    if (zero_cs) {                       // zero only touched cells (saves 256MB memset)
        f32x4* p = (f32x4*)(cellsum + (size_t)cell * COUT);
        f32x4 z; z[0] = z[1] = z[2] = z[3] = 0.f;
#pragma unroll
        for (int q = 0; q < 32; ++q) p[q] = z;
    }
}

// ---- fused GEMM: barrier-free, LDS-free, register-resident ------------------
// 4 waves/block; wave owns 32 rows. A frags loaded straight from global f32,
// converted in-reg; B frags streamed from L2-resident packed weights.
__device__ __forceinline__ us8 cvt8(const float2* v) {
    bf16x8 r;
    r[0] = (__bf16)v[0].x; r[1] = (__bf16)v[0].y;
    r[2] = (__bf16)v[1].x; r[3] = (__bf16)v[1].y;
    r[4] = (__bf16)v[2].x; r[5] = (__bf16)v[2].y;
    r[6] = (__bf16)v[3].x; r[7] = (__bf16)v[3].y;
    return __builtin_bit_cast(us8, r);
}

#define LOADA_FRAG(dst, pr, tl, kg) do{                                  \
    const float* _s = ((kg) == 1016) ? (tl) : ((pr) + (kg));             \
    dst[0] = ((const float2*)_s)[0]; dst[1] = ((const float2*)_s)[1];    \
    dst[2] = ((const float2*)_s)[2]; dst[3] = ((const float2*)_s)[3];    \
}while(0)

#define LOADCHUNK(A00,A01,A10,A11, ch) do{                               \
    const int _k = (ch) * 64 + kgrp * 8;                                 \
    LOADA_FRAG(A00, pr0, tl0, _k);                                       \
    LOADA_FRAG(A01, pr0, tl0, _k + 32);                                  \
    LOADA_FRAG(A10, pr1, tl1, _k);                                       \
    LOADA_FRAG(A11, pr1, tl1, _k + 32);                                  \
}while(0)

#define DOCHUNK(A00,A01,A10,A11, ch) do{                                 \
    us8 b_[2][8];                                                        \
    _Pragma("unroll")                                                    \
    for (int ks = 0; ks < 2; ++ks)                                       \
        _Pragma("unroll")                                                \
        for (int cb = 0; cb < 8; ++cb)                                   \
            b_[ks][cb] = *(const us8*)(pw +                              \
                (((size_t)(ch)*16 + ks*8 + cb)*64 + l)*8);               \
    const us8 a00 = cvt8(A00), a01 = cvt8(A01);                          \
    const us8 a10 = cvt8(A10), a11 = cvt8(A11);                          \
    _Pragma("unroll")                                                    \
    for (int cb = 0; cb < 8; ++cb) {                                     \
        acc0[cb] = __builtin_amdgcn_mfma_f32_16x16x32_bf16(              \
            __builtin_bit_cast(bf16x8, a00), __builtin_bit_cast(bf16x8, b_[0][cb]), acc0[cb], 0,0,0); \
        acc1[cb] = __builtin_amdgcn_mfma_f32_16x16x32_bf16(              \
            __builtin_bit_cast(bf16x8, a10), __builtin_bit_cast(bf16x8, b_[0][cb]), acc1[cb], 0,0,0); \
    }                                                                    \
    _Pragma("unroll")                                                    \
    for (int cb = 0; cb < 8; ++cb) {                                     \
        acc0[cb] = __builtin_amdgcn_mfma_f32_16x16x32_bf16(              \
            __builtin_bit_cast(bf16x8, a01), __builtin_bit_cast(bf16x8, b_[1][cb]), acc0[cb], 0,0,0); \
        acc1[cb] = __builtin_amdgcn_mfma_f32_16x16x32_bf16(              \
            __builtin_bit_cast(bf16x8, a11), __builtin_bit_cast(bf16x8, b_[1][cb]), acc1[cb], 0,0,0); \
    }                                                                    \
}while(0)

template<int DIRECT>
__global__ __launch_bounds__(256, 2) void k_gemm(const float* __restrict__ feats,
                                                 const float* __restrict__ tail,
                                                 const int*   __restrict__ cellid,
                                                 const float* __restrict__ b1,
                                                 const unsigned short* __restrict__ pw,
                                                 float* __restrict__ dst,   // cellsum (A) or out (B)
                                                 float* __restrict__ gstats) {
    __shared__ float lsum[COUT];
    __shared__ float lsq[COUT];
    const int t = threadIdx.x;
    const int w = t >> 6, l = t & 63;
    const int kgrp = l >> 4, l15 = l & 15;
    const int row0 = blockIdx.x * 128 + w * 32;
    if (t < COUT) { lsum[t] = 0.f; lsq[t] = 0.f; }
    __syncthreads();

    const int r0 = row0 + l15, r1 = r0 + 16;
    const float* pr0 = feats + (size_t)r0 * CIN;
    const float* pr1 = feats + (size_t)r1 * CIN;
    const float* tl0 = tail + (size_t)r0 * 8;
    const float* tl1 = tail + (size_t)r1 * 8;

    f32x4 acc0[8], acc1[8];
#pragma unroll
    for (int cb = 0; cb < 8; ++cb) {
#pragma unroll
        for (int d = 0; d < 4; ++d) { acc0[cb][d] = 0.f; acc1[cb][d] = 0.f; }
    }

    float2 X00[4], X01[4], X10[4], X11[4];
    float2 Y00[4], Y01[4], Y10[4], Y11[4];
    LOADCHUNK(X00, X01, X10, X11, 0);
#pragma unroll
    for (int ch = 0; ch < 16; ch += 2) {
        LOADCHUNK(Y00, Y01, Y10, Y11, ch + 1);
        DOCHUNK(X00, X01, X10, X11, ch);
        if (ch + 2 < 16) LOADCHUNK(X00, X01, X10, X11, ch + 2);
        DOCHUNK(Y00, Y01, Y10, Y11, ch + 1);
    }

    // epilogue: bias+relu, scatter to cells, accumulate BN stats
    int c0[4], c1[4];
#pragma unroll
    for (int j = 0; j < 4; ++j) {
        const int m = kgrp * 4 + j;          // C/D: row=(lane>>4)*4+reg, col=lane&15
        c0[j] = cellid[row0 + m];
        c1[j] = cellid[row0 + m + 16];
    }
#pragma unroll
    for (int cb = 0; cb < 8; ++cb) {
        const int c = cb * 16 + l15;
        const float bias = b1[c];
        float s = 0.f, q = 0.f;
#pragma unroll
        for (int j = 0; j < 4; ++j) {
            float v0 = acc0[cb][j] + bias; v0 = v0 > 0.f ? v0 : 0.f;
            float v1 = acc1[cb][j] + bias; v1 = v1 > 0.f ? v1 : 0.f;
            if (DIRECT) {
                const int a = c0[j], bce = c1[j];
                unsafeAtomicAdd(dst + (((size_t)((a  >> 15) * COUT + c)) << 15) + (a  & 32767), v0);
                unsafeAtomicAdd(dst + (((size_t)((bce >> 15) * COUT + c)) << 15) + (bce & 32767), v1);
            } else {
                unsafeAtomicAdd(dst + (size_t)c0[j] * COUT + c, v0);
                unsafeAtomicAdd(dst + (size_t)c1[j] * COUT + c, v1);
            }
            s += v0 + v1; q += v0 * v0 + v1 * v1;
        }
        s += __shfl_xor(s, 16); s += __shfl_xor(s, 32);
        q += __shfl_xor(q, 16); q += __shfl_xor(q, 32);
        if (l < 16) { atomicAdd(&lsum[c], s); atomicAdd(&lsq[c], q); }
    }
    __syncthreads();
    if (t < COUT) {
        unsafeAtomicAdd(gstats + t, lsum[t]);
        unsafeAtomicAdd(gstats + COUT + t, lsq[t]);
    }
}

// ---- finalize BN affine: scale/shift per channel ---------------------------
__global__ void k_stats(const float* __restrict__ gstats, const float* __restrict__ g1,
                        const float* __restrict__ be1, float* __restrict__ ss) {
    const int c = threadIdx.x;   // 128
    const float invn = 1.0f / (float)NPTS;
    const float mean = gstats[c] * invn;
    float var = gstats[COUT + c] * invn - mean * mean;
    var = var < 0.f ? 0.f : var;
    const float sc = g1[c] * rsqrtf(var + 1e-5f);
    ss[c] = sc;
    ss[COUT + c] = be1[c] - mean * sc;
}

// ---- transpose [cell][c] -> [b][c][spatial] with mean + BN affine ----------
// Skips reading cellsum rows with count==0 (output forced to 0 there anyway).
__global__ __launch_bounds__(256) void k_out(const float* __restrict__ cellsum,
                                             const float* __restrict__ count,
                                             const float* __restrict__ ss,
                                             float* __restrict__ out) {
    __shared__ float tile[128 * 128];   // addr(c,j) = c*128 + (j ^ (c&28))
    __shared__ float linv[128];
    __shared__ float lss[256];
    const int t  = threadIdx.x;
    const int s0 = blockIdx.x * 128;
    const int b = s0 >> 15, sp0 = s0 & 32767;
    if (t < 128) {
        const float cn = count[s0 + t];
        linv[t] = cn > 0.f ? 1.0f / cn : 0.f;
    } else {
        const int c = t - 128;
        lss[c] = ss[c]; lss[128 + c] = ss[COUT + c];
    }
    const int q = t & 31, r8 = t >> 5;
#pragma unroll
    for (int rep = 0; rep < 16; ++rep) {
        const int j = r8 + rep * 8;
        if (count[s0 + j] > 0.f) {
            const f32x4 v = *(const f32x4*)&cellsum[(size_t)(s0 + j) * COUT + q * 4];
#pragma unroll
            for (int d = 0; d < 4; ++d) {
                const int c = q * 4 + d;
                tile[c * 128 + (j ^ (c & 28))] = v[d];
            }
        }
    }
    __syncthreads();
#pragma unroll
    for (int p = 0; p < 16; ++p) {
        const int c = p * 8 + r8;
        const float sc = lss[c], sh = lss[128 + c];
        const int u = c & 28;
        const f32x4 vv = *(const f32x4*)&tile[c * 128 + ((q * 4) ^ u)];
        f32x4 o;
#pragma unroll
        for (int d = 0; d < 4; ++d) {
            const float inv = linv[q * 4 + d];
            o[d] = inv > 0.f ? vv[d] * inv * sc + sh : 0.f;
        }
        *(f32x4*)&out[(((size_t)(b * COUT + c)) << 15) + sp0 + q * 4] = o;
    }
}

// ---- fallback normalize when ws too small (scatter went straight to out) ---
__global__ __launch_bounds__(256) void k_norm_inplace(float* __restrict__ out,
                                                      const float* __restrict__ count,
                                                      const float* __restrict__ ss,
                                                      size_t total) {
    const size_t i = ((size_t)blockIdx.x * 256 + threadIdx.x) * 4;
    if (i >= total) return;
    const int c = (int)((i >> 15) & 127);
    const size_t cellb = ((i >> 22) << 15) | (i & 32767);
    f32x4 v = *(f32x4*)&out[i];
    const f32x4 cn = *(const f32x4*)&count[cellb];
    const float sc = ss[c], sh = ss[COUT + c];
#pragma unroll
    for (int d = 0; d < 4; ++d) v[d] = cn[d] > 0.f ? v[d] / cn[d] * sc + sh : 0.f;
    *(f32x4*)&out[i] = v;
}

extern "C" void kernel_launch(void* const* d_in, const int* in_sizes, int n_in,
                              void* d_out, int out_size, void* d_ws, size_t ws_size,
                              hipStream_t stream) {
    const float* xyz   = (const float*)d_in[0];
    const float* nocs  = (const float*)d_in[1];
    const float* feats = (const float*)d_in[2];
    const int*   bidx  = (const int*)d_in[4];
    const float* W1    = (const float*)d_in[6];
    const float* b1    = (const float*)d_in[7];
    const float* g1    = (const float*)d_in[8];
    const float* be1   = (const float*)d_in[9];
    float* out = (float*)d_out;
    float* ws  = (float*)d_ws;

    const size_t CSF = (size_t)NCELLS * COUT;             // 67,108,864 floats
    // plan A layout (floats): cellsum | count | stats | ss | tail | cellid | packedW
    const size_t oA_cs   = 0;
    const size_t oA_cnt  = CSF;
    const size_t oA_st   = oA_cnt + NCELLS;
    const size_t oA_ss   = oA_st + 256;
    const size_t oA_tail = oA_ss + 256;
    const size_t oA_cid  = oA_tail + (size_t)NPTS * 8;
    const size_t oA_pw   = oA_cid + NPTS;
    const size_t needA   = (oA_pw + 65536) * sizeof(float);   // packedW = 131072 u16
    const bool planA = ws_size >= needA;

    // plan B layout (floats): count | stats | ss | tail | cellid | packedW
    const size_t oB_cnt = 0, oB_st = NCELLS, oB_ss = oB_st + 256,
                 oB_tail = oB_ss + 256, oB_cid = oB_tail + (size_t)NPTS * 8,
                 oB_pw = oB_cid + NPTS;

    float* cs  = planA ? ws + oA_cs : nullptr;
    float* cnt = ws + (planA ? oA_cnt : oB_cnt);
    float* st  = ws + (planA ? oA_st : oB_st);
    float* ssb = ws + (planA ? oA_ss : oB_ss);
    float* tl  = ws + (planA ? oA_tail : oB_tail);
    int*   cid = (int*)(ws + (planA ? oA_cid : oB_cid));
    unsigned short* pw = (unsigned short*)(ws + (planA ? oA_pw : oB_pw));

    // zero count + stats (contiguous)
    hipMemsetAsync(cnt, 0, (NCELLS + 256) * sizeof(float), stream);
    if (!planA) hipMemsetAsync(out, 0, (size_t)out_size * sizeof(float), stream);

    k_packW<<<64, 256, 0, stream>>>(W1, pw);
    k_prep<<<NPTS / 256, 256, 0, stream>>>(xyz, nocs, feats, bidx, tl, cid, cnt,
                                           planA ? cs : cnt, planA ? 1 : 0);
    if (planA)
        k_gemm<0><<<NPTS / 128, 256, 0, stream>>>(feats, tl, cid, b1, pw, cs, st);
    else
        k_gemm<1><<<NPTS / 128, 256, 0, stream>>>(feats, tl, cid, b1, pw, out, st);
    k_stats<<<1, 128, 0, stream>>>(st, g1, be1, ssb);
    if (planA)
        k_out<<<NCELLS / 128, 256, 0, stream>>>(cs, cnt, ssb, out);
    else {
        const size_t total = (size_t)out_size;
        k_norm_inplace<<<(unsigned)((total + 1023) / 1024), 256, 0, stream>>>(out, cnt, ssb, total);
    }
    (void)in_sizes; (void)n_in; (void)ws_size; (void)d_in;
}